// Round 1
// baseline (1154.022 us; speedup 1.0000x reference)
//
#include <hip/hip_runtime.h>
#include <hip/hip_bf16.h>

#define NF 128   // feature dim
#define GN 64    // nodes per GEMM block
#define PB 512   // pool partial blocks

// ---------------- CSR build ----------------

__global__ __launch_bounds__(256) void k_count(const int* __restrict__ dst,
                                               int* __restrict__ deg, int E) {
  int e = blockIdx.x * 256 + threadIdx.x;
  if (e < E) atomicAdd(&deg[dst[e]], 1);
}

__global__ __launch_bounds__(1024) void k_scan(const int* __restrict__ deg,
                                               int* __restrict__ row_start, int n) {
  __shared__ int s[1024];
  int t = threadIdx.x;
  int chunk = (n + 1023) >> 10;
  int beg = t * chunk;
  int end = min(beg + chunk, n);
  int sum = 0;
  for (int i = beg; i < end; i++) sum += deg[i];
  s[t] = sum;
  __syncthreads();
  for (int off = 1; off < 1024; off <<= 1) {
    int v = (t >= off) ? s[t - off] : 0;
    __syncthreads();
    s[t] += v;
    __syncthreads();
  }
  int run = s[t] - sum;  // exclusive prefix of this thread's chunk
  for (int i = beg; i < end; i++) { row_start[i] = run; run += deg[i]; }
  if (t == 1023) row_start[n] = s[1023];
}

__global__ __launch_bounds__(256) void k_fill(const int* __restrict__ src,
                                              const int* __restrict__ dst,
                                              const int* __restrict__ row_start,
                                              int* __restrict__ deg,
                                              int* __restrict__ col, int E) {
  int e = blockIdx.x * 256 + threadIdx.x;
  if (e >= E) return;
  int d = dst[e];
  int old = atomicSub(&deg[d], 1);           // consumes deg; slots beg..beg+cnt-1
  col[row_start[d] + old - 1] = src[e];
}

// ---------------- per-layer: gather-mean ----------------
// one wave per node; lane l owns features [2l, 2l+1]

__global__ __launch_bounds__(256) void k_aggr(const float* __restrict__ h,
                                              const int* __restrict__ row_start,
                                              const int* __restrict__ col,
                                              float* __restrict__ aggr, int n) {
  int gw = (blockIdx.x * 256 + threadIdx.x) >> 6;
  int lane = threadIdx.x & 63;
  if (gw >= n) return;
  int beg = row_start[gw], end = row_start[gw + 1];
  float ax = 0.f, ay = 0.f;
  int j = beg;
  for (; j + 2 <= end; j += 2) {   // 2-deep for load ILP
    int s0 = col[j], s1 = col[j + 1];
    float2 v0 = *(const float2*)&h[(size_t)s0 * NF + lane * 2];
    float2 v1 = *(const float2*)&h[(size_t)s1 * NF + lane * 2];
    ax += v0.x + v1.x; ay += v0.y + v1.y;
  }
  if (j < end) {
    int s0 = col[j];
    float2 v0 = *(const float2*)&h[(size_t)s0 * NF + lane * 2];
    ax += v0.x; ay += v0.y;
  }
  int d = end - beg;
  float inv = (d > 0) ? 1.0f / (float)d : 0.0f;
  float2 o; o.x = ax * inv; o.y = ay * inv;
  *(float2*)&aggr[(size_t)gw * NF + lane * 2] = o;
}

// ---------------- per-layer: out = relu(aggr@Wl + hin@Wr + b) ----------------
// 64-node tile in LDS; in-place (hout may alias hin): rows staged before writes,
// and the GEMM is row-local so cross-block aliasing is impossible.
// NOTE: hin/hout intentionally NOT __restrict__ (they may alias).

__global__ __launch_bounds__(256) void k_gemm_relu(const float* hin,
                                                   const float* __restrict__ aggr,
                                                   float* hout,
                                                   const float* __restrict__ Wl,
                                                   const float* __restrict__ Wr,
                                                   const float* __restrict__ bias,
                                                   int n) {
  __shared__ float sH[GN][NF];
  __shared__ float sA[GN][NF];
  int t = threadIdx.x;
  int base = blockIdx.x * GN;
  for (int i = t; i < GN * (NF / 4); i += 256) {
    int r = i >> 5;            // 32 float4 per row
    int c = (i & 31) << 2;
    int node = base + r;
    float4 v = {0, 0, 0, 0}, a = {0, 0, 0, 0};
    if (node < n) {
      v = *(const float4*)&hin[(size_t)node * NF + c];
      a = *(const float4*)&aggr[(size_t)node * NF + c];
    }
    *(float4*)&sH[r][c] = v;
    *(float4*)&sA[r][c] = a;
  }
  __syncthreads();
  int fg = t & 31, ng = t >> 5;
  int f0 = fg << 2, n0 = ng << 3;   // 4 feats x 8 nodes per thread
  float acc[8][4];
  #pragma unroll
  for (int i = 0; i < 8; i++) { acc[i][0] = 0; acc[i][1] = 0; acc[i][2] = 0; acc[i][3] = 0; }
  #pragma unroll 4
  for (int k = 0; k < NF; k++) {
    float4 wl = *(const float4*)&Wl[k * NF + f0];
    float4 wr = *(const float4*)&Wr[k * NF + f0];
    #pragma unroll
    for (int i = 0; i < 8; i++) {
      float a = sA[n0 + i][k];
      float x = sH[n0 + i][k];
      acc[i][0] += a * wl.x; acc[i][1] += a * wl.y; acc[i][2] += a * wl.z; acc[i][3] += a * wl.w;
      acc[i][0] += x * wr.x; acc[i][1] += x * wr.y; acc[i][2] += x * wr.z; acc[i][3] += x * wr.w;
    }
  }
  float4 bb = *(const float4*)&bias[f0];
  #pragma unroll
  for (int i = 0; i < 8; i++) {
    int node = base + n0 + i;
    if (node < n) {
      float4 o;
      o.x = fmaxf(acc[i][0] + bb.x, 0.f);
      o.y = fmaxf(acc[i][1] + bb.y, 0.f);
      o.z = fmaxf(acc[i][2] + bb.z, 0.f);
      o.w = fmaxf(acc[i][3] + bb.w, 0.f);
      *(float4*)&hout[(size_t)node * NF + f0] = o;
    }
  }
}

// ---------------- pool + head ----------------

__global__ __launch_bounds__(128) void k_pool1(const float* __restrict__ h,
                                               float* __restrict__ partial, int n) {
  int f = threadIdx.x;
  float s = 0.f;
  for (int r = blockIdx.x; r < n; r += PB) s += h[(size_t)r * NF + f];
  partial[blockIdx.x * NF + f] = s;
}

__global__ __launch_bounds__(128) void k_pool2(const float* __restrict__ partial,
                                               const float* __restrict__ Wg,
                                               const float* __restrict__ bg,
                                               float* __restrict__ out, int n) {
  __shared__ float g[NF];
  int f = threadIdx.x;
  float s = 0.f;
  for (int b = 0; b < PB; b++) s += partial[b * NF + f];
  g[f] = s / (float)n;
  __syncthreads();
  if (f < 64) {
    float z = bg[f];
    #pragma unroll 4
    for (int k = 0; k < NF; k++) z += g[k] * Wg[k * 64 + f];
    out[f] = 1.0f / (1.0f + expf(-z));
  }
}

// ---------------- launch ----------------

extern "C" void kernel_launch(void* const* d_in, const int* in_sizes, int n_in,
                              void* d_out, int out_size, void* d_ws, size_t ws_size,
                              hipStream_t stream) {
  const float* x   = (const float*)d_in[0];
  const int*   ei  = (const int*)d_in[1];
  const float* Wl1 = (const float*)d_in[2];
  const float* Wr1 = (const float*)d_in[3];
  const float* b1  = (const float*)d_in[4];
  const float* Wl2 = (const float*)d_in[5];
  const float* Wr2 = (const float*)d_in[6];
  const float* b2  = (const float*)d_in[7];
  const float* Wl3 = (const float*)d_in[8];
  const float* Wr3 = (const float*)d_in[9];
  const float* b3  = (const float*)d_in[10];
  const float* Wg  = (const float*)d_in[11];
  const float* bg  = (const float*)d_in[12];
  float* out = (float*)d_out;

  int n = in_sizes[0] / NF;      // 100000
  int E = in_sizes[1] / 2;       // 1600000
  const int* srcp = ei;
  const int* dstp = ei + E;

  // workspace carve-up (aligned to 256B)
  char* w = (char*)d_ws;
  size_t off = 0;
  auto carve = [&](size_t bytes) -> void* {
    off = (off + 255) & ~(size_t)255;
    void* p = w + off;
    off += bytes;
    return p;
  };
  int*   col       = (int*)  carve((size_t)E * 4);
  int*   row_start = (int*)  carve((size_t)(n + 1) * 4);
  int*   deg       = (int*)  carve((size_t)n * 4);
  float* aggr      = (float*)carve((size_t)n * NF * 4);
  float* h         = (float*)carve((size_t)n * NF * 4);
  float* partial   = (float*)carve((size_t)PB * NF * 4);

  int eg = (E + 255) / 256;
  int ag = (n + 3) / 4;           // 4 waves (nodes) per 256-thread block
  int gg = (n + GN - 1) / GN;

  // CSR build (once per launch)
  hipMemsetAsync(deg, 0, (size_t)n * 4, stream);
  k_count<<<eg, 256, 0, stream>>>(dstp, deg, E);
  k_scan<<<1, 1024, 0, stream>>>(deg, row_start, n);
  k_fill<<<eg, 256, 0, stream>>>(srcp, dstp, row_start, deg, col, E);

  // layer 1: x -> h
  k_aggr<<<ag, 256, 0, stream>>>(x, row_start, col, aggr, n);
  k_gemm_relu<<<gg, 256, 0, stream>>>(x, aggr, h, Wl1, Wr1, b1, n);
  // layer 2: h -> h (in-place safe)
  k_aggr<<<ag, 256, 0, stream>>>(h, row_start, col, aggr, n);
  k_gemm_relu<<<gg, 256, 0, stream>>>(h, aggr, h, Wl2, Wr2, b2, n);
  // layer 3: h -> h
  k_aggr<<<ag, 256, 0, stream>>>(h, row_start, col, aggr, n);
  k_gemm_relu<<<gg, 256, 0, stream>>>(h, aggr, h, Wl3, Wr3, b3, n);

  // pool + head
  k_pool1<<<PB, 128, 0, stream>>>(h, partial, n);
  k_pool2<<<1, 128, 0, stream>>>(partial, Wg, bg, out, n);
}

// Round 2
// 1024.578 us; speedup vs baseline: 1.1263x; 1.1263x over previous
//
#include <hip/hip_runtime.h>
#include <hip/hip_bf16.h>

#define NF 128   // feature dim
#define GN 64    // nodes per GEMM block
#define PB 512   // pool partial blocks
#define SCAN_COVER 1024  // elems per scan block (256 thr x 4)

// ---------------- CSR build ----------------

__global__ __launch_bounds__(256) void k_count(const int* __restrict__ dst,
                                               int* __restrict__ deg, int E) {
  int e = blockIdx.x * 256 + threadIdx.x;
  if (e < E) atomicAdd(&deg[dst[e]], 1);
}

// multi-block exclusive scan of deg[0..n-1] -> row_start[0..n]
__global__ __launch_bounds__(256) void k_scan1(const int* __restrict__ deg,
                                               int* __restrict__ bsum, int n) {
  __shared__ int s[256];
  int t = threadIdx.x;
  int base = blockIdx.x * SCAN_COVER + t * 4;
  int sum = 0;
  #pragma unroll
  for (int i = 0; i < 4; i++) { int idx = base + i; if (idx < n) sum += deg[idx]; }
  s[t] = sum;
  __syncthreads();
  for (int off = 128; off > 0; off >>= 1) {
    if (t < off) s[t] += s[t + off];
    __syncthreads();
  }
  if (t == 0) bsum[blockIdx.x] = s[0];
}

__global__ __launch_bounds__(128) void k_scan2(int* __restrict__ bsum,
                                               int* __restrict__ row_start,
                                               int nb, int n) {
  __shared__ int s[128];
  int t = threadIdx.x;
  int v = (t < nb) ? bsum[t] : 0;
  s[t] = v;
  __syncthreads();
  for (int off = 1; off < 128; off <<= 1) {
    int u = (t >= off) ? s[t - off] : 0;
    __syncthreads();
    s[t] += u;
    __syncthreads();
  }
  if (t < nb) bsum[t] = s[t] - v;          // exclusive block prefix
  if (t == 127) row_start[n] = s[127];     // total edge count
}

__global__ __launch_bounds__(256) void k_scan3(const int* __restrict__ deg,
                                               const int* __restrict__ bsum,
                                               int* __restrict__ row_start, int n) {
  __shared__ int s[256];
  int t = threadIdx.x;
  int base = blockIdx.x * SCAN_COVER + t * 4;
  int d[4];
  int sum = 0;
  #pragma unroll
  for (int i = 0; i < 4; i++) {
    int idx = base + i;
    d[i] = (idx < n) ? deg[idx] : 0;
    sum += d[i];
  }
  s[t] = sum;
  __syncthreads();
  for (int off = 1; off < 256; off <<= 1) {
    int u = (t >= off) ? s[t - off] : 0;
    __syncthreads();
    s[t] += u;
    __syncthreads();
  }
  int pre = s[t] - sum + bsum[blockIdx.x];
  #pragma unroll
  for (int i = 0; i < 4; i++) {
    int idx = base + i;
    if (idx < n) row_start[idx] = pre;
    pre += d[i];
  }
}

__global__ __launch_bounds__(256) void k_fill(const int* __restrict__ src,
                                              const int* __restrict__ dst,
                                              const int* __restrict__ row_start,
                                              int* __restrict__ deg,
                                              int* __restrict__ col, int E) {
  int e = blockIdx.x * 256 + threadIdx.x;
  if (e >= E) return;
  int d = dst[e];
  int old = atomicSub(&deg[d], 1);           // consumes deg; slots beg..beg+cnt-1
  col[row_start[d] + old - 1] = src[e];
}

// ---------------- per-layer: gather-mean ----------------
// one wave per node; lane l owns features [2l, 2l+1]

__global__ __launch_bounds__(256) void k_aggr(const float* __restrict__ h,
                                              const int* __restrict__ row_start,
                                              const int* __restrict__ col,
                                              float* __restrict__ aggr, int n) {
  int gw = (blockIdx.x * 256 + threadIdx.x) >> 6;
  int lane = threadIdx.x & 63;
  if (gw >= n) return;
  int beg = row_start[gw], end = row_start[gw + 1];
  float ax = 0.f, ay = 0.f;
  int j = beg;
  for (; j + 4 <= end; j += 4) {   // 4-deep for load ILP
    int s0 = col[j], s1 = col[j + 1], s2 = col[j + 2], s3 = col[j + 3];
    float2 v0 = *(const float2*)&h[(size_t)s0 * NF + lane * 2];
    float2 v1 = *(const float2*)&h[(size_t)s1 * NF + lane * 2];
    float2 v2 = *(const float2*)&h[(size_t)s2 * NF + lane * 2];
    float2 v3 = *(const float2*)&h[(size_t)s3 * NF + lane * 2];
    ax += v0.x + v1.x + v2.x + v3.x;
    ay += v0.y + v1.y + v2.y + v3.y;
  }
  for (; j < end; j++) {
    int s0 = col[j];
    float2 v0 = *(const float2*)&h[(size_t)s0 * NF + lane * 2];
    ax += v0.x; ay += v0.y;
  }
  int d = end - beg;
  float inv = (d > 0) ? 1.0f / (float)d : 0.0f;
  float2 o; o.x = ax * inv; o.y = ay * inv;
  *(float2*)&aggr[(size_t)gw * NF + lane * 2] = o;
}

// ---------------- per-layer: out = relu(aggr@Wl + hin@Wr + b) ----------------
// 64-node tile in LDS; in-place (hout may alias hin): rows staged before writes,
// and the GEMM is row-local so cross-block aliasing is impossible.
// NOTE: hin/hout intentionally NOT __restrict__ (they may alias).

__global__ __launch_bounds__(256) void k_gemm_relu(const float* hin,
                                                   const float* __restrict__ aggr,
                                                   float* hout,
                                                   const float* __restrict__ Wl,
                                                   const float* __restrict__ Wr,
                                                   const float* __restrict__ bias,
                                                   int n) {
  __shared__ float sH[GN][NF];
  __shared__ float sA[GN][NF];
  int t = threadIdx.x;
  int base = blockIdx.x * GN;
  for (int i = t; i < GN * (NF / 4); i += 256) {
    int r = i >> 5;            // 32 float4 per row
    int c = (i & 31) << 2;
    int node = base + r;
    float4 v = {0, 0, 0, 0}, a = {0, 0, 0, 0};
    if (node < n) {
      v = *(const float4*)&hin[(size_t)node * NF + c];
      a = *(const float4*)&aggr[(size_t)node * NF + c];
    }
    *(float4*)&sH[r][c] = v;
    *(float4*)&sA[r][c] = a;
  }
  __syncthreads();
  int fg = t & 31, ng = t >> 5;
  int f0 = fg << 2, n0 = ng << 3;   // 4 feats x 8 nodes per thread
  float acc[8][4];
  #pragma unroll
  for (int i = 0; i < 8; i++) { acc[i][0] = 0; acc[i][1] = 0; acc[i][2] = 0; acc[i][3] = 0; }
  #pragma unroll 4
  for (int k = 0; k < NF; k++) {
    float4 wl = *(const float4*)&Wl[k * NF + f0];
    float4 wr = *(const float4*)&Wr[k * NF + f0];
    #pragma unroll
    for (int i = 0; i < 8; i++) {
      float a = sA[n0 + i][k];
      float x = sH[n0 + i][k];
      acc[i][0] += a * wl.x; acc[i][1] += a * wl.y; acc[i][2] += a * wl.z; acc[i][3] += a * wl.w;
      acc[i][0] += x * wr.x; acc[i][1] += x * wr.y; acc[i][2] += x * wr.z; acc[i][3] += x * wr.w;
    }
  }
  float4 bb = *(const float4*)&bias[f0];
  #pragma unroll
  for (int i = 0; i < 8; i++) {
    int node = base + n0 + i;
    if (node < n) {
      float4 o;
      o.x = fmaxf(acc[i][0] + bb.x, 0.f);
      o.y = fmaxf(acc[i][1] + bb.y, 0.f);
      o.z = fmaxf(acc[i][2] + bb.z, 0.f);
      o.w = fmaxf(acc[i][3] + bb.w, 0.f);
      *(float4*)&hout[(size_t)node * NF + f0] = o;
    }
  }
}

// ---------------- pool + head ----------------

__global__ __launch_bounds__(128) void k_pool1(const float* __restrict__ h,
                                               float* __restrict__ partial, int n) {
  int f = threadIdx.x;
  float s = 0.f;
  for (int r = blockIdx.x; r < n; r += PB) s += h[(size_t)r * NF + f];
  partial[blockIdx.x * NF + f] = s;
}

__global__ __launch_bounds__(128) void k_pool2(const float* __restrict__ partial,
                                               const float* __restrict__ Wg,
                                               const float* __restrict__ bg,
                                               float* __restrict__ out, int n) {
  __shared__ float g[NF];
  int f = threadIdx.x;
  float s = 0.f;
  for (int b = 0; b < PB; b++) s += partial[b * NF + f];
  g[f] = s / (float)n;
  __syncthreads();
  if (f < 64) {
    float z = bg[f];
    #pragma unroll 4
    for (int k = 0; k < NF; k++) z += g[k] * Wg[k * 64 + f];
    out[f] = 1.0f / (1.0f + expf(-z));
  }
}

// ---------------- launch ----------------

extern "C" void kernel_launch(void* const* d_in, const int* in_sizes, int n_in,
                              void* d_out, int out_size, void* d_ws, size_t ws_size,
                              hipStream_t stream) {
  const float* x   = (const float*)d_in[0];
  const int*   ei  = (const int*)d_in[1];
  const float* Wl1 = (const float*)d_in[2];
  const float* Wr1 = (const float*)d_in[3];
  const float* b1  = (const float*)d_in[4];
  const float* Wl2 = (const float*)d_in[5];
  const float* Wr2 = (const float*)d_in[6];
  const float* b2  = (const float*)d_in[7];
  const float* Wl3 = (const float*)d_in[8];
  const float* Wr3 = (const float*)d_in[9];
  const float* b3  = (const float*)d_in[10];
  const float* Wg  = (const float*)d_in[11];
  const float* bg  = (const float*)d_in[12];
  float* out = (float*)d_out;

  int n = in_sizes[0] / NF;      // 100000
  int E = in_sizes[1] / 2;       // 1600000
  const int* srcp = ei;
  const int* dstp = ei + E;

  // workspace carve-up (aligned to 256B)
  char* w = (char*)d_ws;
  size_t off = 0;
  auto carve = [&](size_t bytes) -> void* {
    off = (off + 255) & ~(size_t)255;
    void* p = w + off;
    off += bytes;
    return p;
  };
  int nb = (n + SCAN_COVER - 1) / SCAN_COVER;   // 98 scan blocks
  int*   col       = (int*)  carve((size_t)E * 4);
  int*   row_start = (int*)  carve((size_t)(n + 1) * 4);
  int*   deg       = (int*)  carve((size_t)n * 4);
  int*   bsum      = (int*)  carve((size_t)nb * 4);
  float* aggr      = (float*)carve((size_t)n * NF * 4);
  float* h         = (float*)carve((size_t)n * NF * 4);
  float* partial   = (float*)carve((size_t)PB * NF * 4);

  int eg = (E + 255) / 256;
  int ag = (n + 3) / 4;           // 4 waves (nodes) per 256-thread block
  int gg = (n + GN - 1) / GN;

  // CSR build (once per launch)
  hipMemsetAsync(deg, 0, (size_t)n * 4, stream);
  k_count<<<eg, 256, 0, stream>>>(dstp, deg, E);
  k_scan1<<<nb, 256, 0, stream>>>(deg, bsum, n);
  k_scan2<<<1, 128, 0, stream>>>(bsum, row_start, nb, n);
  k_scan3<<<nb, 256, 0, stream>>>(deg, bsum, row_start, n);
  k_fill<<<eg, 256, 0, stream>>>(srcp, dstp, row_start, deg, col, E);

  // layer 1: x -> h
  k_aggr<<<ag, 256, 0, stream>>>(x, row_start, col, aggr, n);
  k_gemm_relu<<<gg, 256, 0, stream>>>(x, aggr, h, Wl1, Wr1, b1, n);
  // layer 2: h -> h (in-place safe)
  k_aggr<<<ag, 256, 0, stream>>>(h, row_start, col, aggr, n);
  k_gemm_relu<<<gg, 256, 0, stream>>>(h, aggr, h, Wl2, Wr2, b2, n);
  // layer 3: h -> h
  k_aggr<<<ag, 256, 0, stream>>>(h, row_start, col, aggr, n);
  k_gemm_relu<<<gg, 256, 0, stream>>>(h, aggr, h, Wl3, Wr3, b3, n);

  // pool + head
  k_pool1<<<PB, 128, 0, stream>>>(h, partial, n);
  k_pool2<<<1, 128, 0, stream>>>(partial, Wg, bg, out, n);
}

// Round 4
// 738.053 us; speedup vs baseline: 1.5636x; 1.3882x over previous
//
#include <hip/hip_runtime.h>
#include <hip/hip_bf16.h>

#define NF 128   // feature dim
#define PB 512   // pool partial blocks
#define SCAN_COVER 1024  // elems per scan block (256 thr x 4)
#define GEMM_BLOCKS 512  // persistent-ish gemm grid

typedef __attribute__((ext_vector_type(8))) short bf16x8;
typedef __attribute__((ext_vector_type(4))) float f32x4;

__device__ inline float b2f(ushort u) { return __uint_as_float(((uint)u) << 16); }
__device__ inline ushort f2bf(float f) {           // round-to-nearest-even
  uint u = __float_as_uint(f);
  return (ushort)((u + 0x7fffu + ((u >> 16) & 1u)) >> 16);
}

// ---------------- x -> bf16 ----------------
__global__ __launch_bounds__(256) void k_cvt(const float* __restrict__ x,
                                             ushort* __restrict__ xb, int total4) {
  for (int i = blockIdx.x * 256 + threadIdx.x; i < total4; i += gridDim.x * 256) {
    float4 v = *(const float4*)&x[(size_t)i * 4];
    ushort4 o;
    o.x = f2bf(v.x); o.y = f2bf(v.y); o.z = f2bf(v.z); o.w = f2bf(v.w);
    *(ushort4*)&xb[(size_t)i * 4] = o;
  }
}

// ---------------- CSR build ----------------
__global__ __launch_bounds__(256) void k_count(const int* __restrict__ dst,
                                               int* __restrict__ deg, int E) {
  int e = blockIdx.x * 256 + threadIdx.x;
  if (e < E) atomicAdd(&deg[dst[e]], 1);
}

__global__ __launch_bounds__(256) void k_scan1(const int* __restrict__ deg,
                                               int* __restrict__ bsum, int n) {
  __shared__ int s[256];
  int t = threadIdx.x;
  int base = blockIdx.x * SCAN_COVER + t * 4;
  int sum = 0;
  #pragma unroll
  for (int i = 0; i < 4; i++) { int idx = base + i; if (idx < n) sum += deg[idx]; }
  s[t] = sum;
  __syncthreads();
  for (int off = 128; off > 0; off >>= 1) {
    if (t < off) s[t] += s[t + off];
    __syncthreads();
  }
  if (t == 0) bsum[blockIdx.x] = s[0];
}

__global__ __launch_bounds__(128) void k_scan2(int* __restrict__ bsum,
                                               int* __restrict__ row_start,
                                               int nb, int n) {
  __shared__ int s[128];
  int t = threadIdx.x;
  int v = (t < nb) ? bsum[t] : 0;
  s[t] = v;
  __syncthreads();
  for (int off = 1; off < 128; off <<= 1) {
    int u = (t >= off) ? s[t - off] : 0;
    __syncthreads();
    s[t] += u;
    __syncthreads();
  }
  if (t < nb) bsum[t] = s[t] - v;          // exclusive block prefix
  if (t == 127) row_start[n] = s[127];
}

__global__ __launch_bounds__(256) void k_scan3(const int* __restrict__ deg,
                                               const int* __restrict__ bsum,
                                               int* __restrict__ row_start, int n) {
  __shared__ int s[256];
  int t = threadIdx.x;
  int base = blockIdx.x * SCAN_COVER + t * 4;
  int d[4];
  int sum = 0;
  #pragma unroll
  for (int i = 0; i < 4; i++) {
    int idx = base + i;
    d[i] = (idx < n) ? deg[idx] : 0;
    sum += d[i];
  }
  s[t] = sum;
  __syncthreads();
  for (int off = 1; off < 256; off <<= 1) {
    int u = (t >= off) ? s[t - off] : 0;
    __syncthreads();
    s[t] += u;
    __syncthreads();
  }
  int pre = s[t] - sum + bsum[blockIdx.x];
  #pragma unroll
  for (int i = 0; i < 4; i++) {
    int idx = base + i;
    if (idx < n) row_start[idx] = pre;
    pre += d[i];
  }
}

__global__ __launch_bounds__(256) void k_fill(const int* __restrict__ src,
                                              const int* __restrict__ dst,
                                              const int* __restrict__ row_start,
                                              int* __restrict__ deg,
                                              int* __restrict__ col, int E) {
  int e = blockIdx.x * 256 + threadIdx.x;
  if (e >= E) return;
  int d = dst[e];
  int old = atomicSub(&deg[d], 1);
  col[row_start[d] + old - 1] = src[e];
}

// ---------------- gather-mean (bf16 in/out, fp32 accum) ----------------
// one wave per node; lane l owns features [2l, 2l+1] (one dword)
__global__ __launch_bounds__(256) void k_aggr_bf(const ushort* __restrict__ h,
                                                 const int* __restrict__ row_start,
                                                 const int* __restrict__ col,
                                                 ushort* __restrict__ aggr, int n) {
  int gw = (blockIdx.x * 256 + threadIdx.x) >> 6;
  int lane = threadIdx.x & 63;
  if (gw >= n) return;
  int beg = row_start[gw], end = row_start[gw + 1];
  float ax = 0.f, ay = 0.f;
  int j = beg;
  for (; j + 4 <= end; j += 4) {
    uint v0 = *(const uint*)&h[(size_t)col[j]     * NF + lane * 2];
    uint v1 = *(const uint*)&h[(size_t)col[j + 1] * NF + lane * 2];
    uint v2 = *(const uint*)&h[(size_t)col[j + 2] * NF + lane * 2];
    uint v3 = *(const uint*)&h[(size_t)col[j + 3] * NF + lane * 2];
    ax += __uint_as_float(v0 << 16) + __uint_as_float(v1 << 16) +
          __uint_as_float(v2 << 16) + __uint_as_float(v3 << 16);
    ay += __uint_as_float(v0 & 0xffff0000u) + __uint_as_float(v1 & 0xffff0000u) +
          __uint_as_float(v2 & 0xffff0000u) + __uint_as_float(v3 & 0xffff0000u);
  }
  for (; j < end; j++) {
    uint v0 = *(const uint*)&h[(size_t)col[j] * NF + lane * 2];
    ax += __uint_as_float(v0 << 16);
    ay += __uint_as_float(v0 & 0xffff0000u);
  }
  int d = end - beg;
  float inv = (d > 0) ? 1.0f / (float)d : 0.0f;
  uint o = (uint)f2bf(ax * inv) | ((uint)f2bf(ay * inv) << 16);
  *(uint*)&aggr[(size_t)gw * NF + lane * 2] = o;
}

// ---------------- MFMA GEMM: hout = relu([aggr|hin] @ [Wl;Wr] + b) ----------------
// 256 thr = 4 waves; wave w owns cols [32w, 32w+32); B-frags in regs (from
// LDS-transposed, XOR-swizzled Wt); A streamed from global; slab = 64 rows.
#define WSWZ(c, kbyte) (((c) << 9) + ((kbyte) ^ (((c) & 7) << 4)))

__global__ __launch_bounds__(256) void k_gemm_mfma(const ushort* __restrict__ aggr,
                                                   const ushort* __restrict__ hin,
                                                   ushort* __restrict__ hout,
                                                   const float* __restrict__ Wl,
                                                   const float* __restrict__ Wr,
                                                   const float* __restrict__ bias,
                                                   int n, int nslab) {
  __shared__ ushort Wt[128 * 256];   // [col][k] bf16, 64 KB, XOR-swizzled
  int t = threadIdx.x;
  // load + transpose + cvt weights: Wl -> k 0..127, Wr -> k 128..255
  for (int i = t; i < 128 * 128; i += 256) {
    int k = i >> 7, c = i & 127;
    *(ushort*)((char*)Wt + WSWZ(c, k * 2))         = f2bf(Wl[i]);
    *(ushort*)((char*)Wt + WSWZ(c, (k + 128) * 2)) = f2bf(Wr[i]);
  }
  __syncthreads();

  int wv = t >> 6, lane = t & 63;
  int c0 = wv * 32;
  int lrow = lane & 15, lhi = lane >> 4;

  // B fragments: lane holds B[k = kc*32 + lhi*8 + j][col = c0 + ct*16 + lrow]
  bf16x8 bfrag[8][2];
  #pragma unroll
  for (int kc = 0; kc < 8; kc++)
    #pragma unroll
    for (int ct = 0; ct < 2; ct++) {
      int colv = c0 + ct * 16 + lrow;
      int kbyte = (kc * 32 + lhi * 8) * 2;
      bfrag[kc][ct] = *(const bf16x8*)((const char*)Wt + WSWZ(colv, kbyte));
    }
  float bv0 = bias[c0 + lrow], bv1 = bias[c0 + 16 + lrow];

  for (int sl = blockIdx.x; sl < nslab; sl += GEMM_BLOCKS) {
    int row0 = sl * 64;
    f32x4 acc[4][2];
    #pragma unroll
    for (int rt = 0; rt < 4; rt++)
      #pragma unroll
      for (int ct = 0; ct < 2; ct++) acc[rt][ct] = (f32x4){0.f, 0.f, 0.f, 0.f};

    #pragma unroll
    for (int kc = 0; kc < 8; kc++) {
      const ushort* Asrc = (kc < 4) ? aggr : hin;
      int k0 = (kc & 3) * 32 + lhi * 8;
      bf16x8 af[4];
      #pragma unroll
      for (int rt = 0; rt < 4; rt++) {
        int r = row0 + rt * 16 + lrow;
        if (r >= n) r = n - 1;
        af[rt] = *(const bf16x8*)&Asrc[(size_t)r * NF + k0];
      }
      #pragma unroll
      for (int rt = 0; rt < 4; rt++) {
        acc[rt][0] = __builtin_amdgcn_mfma_f32_16x16x32_bf16(af[rt], bfrag[kc][0], acc[rt][0], 0, 0, 0);
        acc[rt][1] = __builtin_amdgcn_mfma_f32_16x16x32_bf16(af[rt], bfrag[kc][1], acc[rt][1], 0, 0, 0);
      }
    }
    // C/D: col = lane&15, row = (lane>>4)*4 + reg   [m89-verified]
    #pragma unroll
    for (int rt = 0; rt < 4; rt++) {
      int rbase = row0 + rt * 16 + lhi * 4;
      #pragma unroll
      for (int r = 0; r < 4; r++) {
        int row = rbase + r;
        if (row < n) {
          hout[(size_t)row * NF + c0 + lrow]      = f2bf(fmaxf(acc[rt][0][r] + bv0, 0.f));
          hout[(size_t)row * NF + c0 + 16 + lrow] = f2bf(fmaxf(acc[rt][1][r] + bv1, 0.f));
        }
      }
    }
  }
}

// ---------------- pool + head ----------------
__global__ __launch_bounds__(128) void k_pool1(const ushort* __restrict__ h,
                                               float* __restrict__ partial, int n) {
  int f = threadIdx.x;
  float s = 0.f;
  for (int r = blockIdx.x; r < n; r += PB) s += b2f(h[(size_t)r * NF + f]);
  partial[blockIdx.x * NF + f] = s;
}

__global__ __launch_bounds__(128) void k_pool2(const float* __restrict__ partial,
                                               const float* __restrict__ Wg,
                                               const float* __restrict__ bg,
                                               float* __restrict__ out, int n) {
  __shared__ float g[NF];
  int f = threadIdx.x;
  float s = 0.f;
  for (int b = 0; b < PB; b++) s += partial[b * NF + f];
  g[f] = s / (float)n;
  __syncthreads();
  if (f < 64) {
    float z = bg[f];
    #pragma unroll 4
    for (int k = 0; k < NF; k++) z += g[k] * Wg[k * 64 + f];
    out[f] = 1.0f / (1.0f + expf(-z));
  }
}

// ---------------- launch ----------------
extern "C" void kernel_launch(void* const* d_in, const int* in_sizes, int n_in,
                              void* d_out, int out_size, void* d_ws, size_t ws_size,
                              hipStream_t stream) {
  const float* x   = (const float*)d_in[0];
  const int*   ei  = (const int*)d_in[1];
  const float* Wl1 = (const float*)d_in[2];
  const float* Wr1 = (const float*)d_in[3];
  const float* b1  = (const float*)d_in[4];
  const float* Wl2 = (const float*)d_in[5];
  const float* Wr2 = (const float*)d_in[6];
  const float* b2  = (const float*)d_in[7];
  const float* Wl3 = (const float*)d_in[8];
  const float* Wr3 = (const float*)d_in[9];
  const float* b3  = (const float*)d_in[10];
  const float* Wg  = (const float*)d_in[11];
  const float* bg  = (const float*)d_in[12];
  float* out = (float*)d_out;

  int n = in_sizes[0] / NF;      // 100000
  int E = in_sizes[1] / 2;       // 1600000
  const int* srcp = ei;
  const int* dstp = ei + E;

  char* w = (char*)d_ws;
  size_t off = 0;
  auto carve = [&](size_t bytes) -> void* {
    off = (off + 255) & ~(size_t)255;
    void* p = w + off;
    off += bytes;
    return p;
  };
  int nb = (n + SCAN_COVER - 1) / SCAN_COVER;
  int*    col       = (int*)   carve((size_t)E * 4);
  int*    row_start = (int*)   carve((size_t)(n + 1) * 4);
  int*    deg       = (int*)   carve((size_t)n * 4);
  int*    bsum      = (int*)   carve((size_t)nb * 4);
  ushort* xb        = (ushort*)carve((size_t)n * NF * 2);
  ushort* aggr      = (ushort*)carve((size_t)n * NF * 2);
  ushort* ha        = (ushort*)carve((size_t)n * NF * 2);
  ushort* hb        = (ushort*)carve((size_t)n * NF * 2);
  float*  partial   = (float*) carve((size_t)PB * NF * 4);

  int eg = (E + 255) / 256;
  int ag = (n + 3) / 4;
  int nslab = (n + 63) / 64;

  // convert x to bf16
  k_cvt<<<2048, 256, 0, stream>>>(x, xb, n * NF / 4);

  // CSR build
  hipMemsetAsync(deg, 0, (size_t)n * 4, stream);
  k_count<<<eg, 256, 0, stream>>>(dstp, deg, E);
  k_scan1<<<nb, 256, 0, stream>>>(deg, bsum, n);
  k_scan2<<<1, 128, 0, stream>>>(bsum, row_start, nb, n);
  k_scan3<<<nb, 256, 0, stream>>>(deg, bsum, row_start, n);
  k_fill<<<eg, 256, 0, stream>>>(srcp, dstp, row_start, deg, col, E);

  // layer 1: xb -> ha
  k_aggr_bf<<<ag, 256, 0, stream>>>(xb, row_start, col, aggr, n);
  k_gemm_mfma<<<GEMM_BLOCKS, 256, 0, stream>>>(aggr, xb, ha, Wl1, Wr1, b1, n, nslab);
  // layer 2: ha -> hb
  k_aggr_bf<<<ag, 256, 0, stream>>>(ha, row_start, col, aggr, n);
  k_gemm_mfma<<<GEMM_BLOCKS, 256, 0, stream>>>(aggr, ha, hb, Wl2, Wr2, b2, n, nslab);
  // layer 3: hb -> ha
  k_aggr_bf<<<ag, 256, 0, stream>>>(hb, row_start, col, aggr, n);
  k_gemm_mfma<<<GEMM_BLOCKS, 256, 0, stream>>>(aggr, hb, ha, Wl3, Wr3, b3, n, nslab);

  // pool + head
  k_pool1<<<PB, 128, 0, stream>>>(ha, partial, n);
  k_pool2<<<1, 128, 0, stream>>>(partial, Wg, bg, out, n);
}

// Round 5
// 733.079 us; speedup vs baseline: 1.5742x; 1.0068x over previous
//
#include <hip/hip_runtime.h>
#include <hip/hip_bf16.h>

#define NF 128   // feature dim
#define PB 512   // pool partial blocks
#define SCAN_COVER 1024  // elems per scan block (256 thr x 4)
#define GEMM_BLOCKS 512  // persistent-ish gemm grid
#define BKT_SHIFT 7      // 128 nodes per bucket
#define BKT_NODES 128

typedef __attribute__((ext_vector_type(8))) short bf16x8;
typedef __attribute__((ext_vector_type(4))) float f32x4;

__device__ inline float b2f(ushort u) { return __uint_as_float(((uint)u) << 16); }
__device__ inline ushort f2bf(float f) {           // round-to-nearest-even
  uint u = __float_as_uint(f);
  return (ushort)((u + 0x7fffu + ((u >> 16) & 1u)) >> 16);
}

// ---------------- x -> bf16 ----------------
__global__ __launch_bounds__(256) void k_cvt(const float* __restrict__ x,
                                             ushort* __restrict__ xb, int total4) {
  for (int i = blockIdx.x * 256 + threadIdx.x; i < total4; i += gridDim.x * 256) {
    float4 v = *(const float4*)&x[(size_t)i * 4];
    ushort4 o;
    o.x = f2bf(v.x); o.y = f2bf(v.y); o.z = f2bf(v.z); o.w = f2bf(v.w);
    *(ushort4*)&xb[(size_t)i * 4] = o;
  }
}

// ---------------- CSR build ----------------
__global__ __launch_bounds__(256) void k_count(const int* __restrict__ dst,
                                               int* __restrict__ deg, int E) {
  int e = blockIdx.x * 256 + threadIdx.x;
  if (e < E) atomicAdd(&deg[dst[e]], 1);
}

__global__ __launch_bounds__(256) void k_scan1(const int* __restrict__ deg,
                                               int* __restrict__ bsum, int n) {
  __shared__ int s[256];
  int t = threadIdx.x;
  int base = blockIdx.x * SCAN_COVER + t * 4;
  int sum = 0;
  #pragma unroll
  for (int i = 0; i < 4; i++) { int idx = base + i; if (idx < n) sum += deg[idx]; }
  s[t] = sum;
  __syncthreads();
  for (int off = 128; off > 0; off >>= 1) {
    if (t < off) s[t] += s[t + off];
    __syncthreads();
  }
  if (t == 0) bsum[blockIdx.x] = s[0];
}

__global__ __launch_bounds__(128) void k_scan2(int* __restrict__ bsum,
                                               int* __restrict__ row_start,
                                               int nb, int n) {
  __shared__ int s[128];
  int t = threadIdx.x;
  int v = (t < nb) ? bsum[t] : 0;
  s[t] = v;
  __syncthreads();
  for (int off = 1; off < 128; off <<= 1) {
    int u = (t >= off) ? s[t - off] : 0;
    __syncthreads();
    s[t] += u;
    __syncthreads();
  }
  if (t < nb) bsum[t] = s[t] - v;          // exclusive block prefix
  if (t == 127) row_start[n] = s[127];
}

__global__ __launch_bounds__(256) void k_scan3(const int* __restrict__ deg,
                                               const int* __restrict__ bsum,
                                               int* __restrict__ row_start, int n) {
  __shared__ int s[256];
  int t = threadIdx.x;
  int base = blockIdx.x * SCAN_COVER + t * 4;
  int d[4];
  int sum = 0;
  #pragma unroll
  for (int i = 0; i < 4; i++) {
    int idx = base + i;
    d[i] = (idx < n) ? deg[idx] : 0;
    sum += d[i];
  }
  s[t] = sum;
  __syncthreads();
  for (int off = 1; off < 256; off <<= 1) {
    int u = (t >= off) ? s[t - off] : 0;
    __syncthreads();
    s[t] += u;
    __syncthreads();
  }
  int pre = s[t] - sum + bsum[blockIdx.x];
  #pragma unroll
  for (int i = 0; i < 4; i++) {
    int idx = base + i;
    if (idx < n) row_start[idx] = pre;
    pre += d[i];
  }
}

// bucket cursors: one per 64B line to avoid atomic line contention
__global__ __launch_bounds__(256) void k_bcur_init(const int* __restrict__ row_start,
                                                   int* __restrict__ bcur, int nbkt, int n) {
  int b = blockIdx.x * 256 + threadIdx.x;
  if (b < nbkt) {
    int node = b << BKT_SHIFT;
    bcur[b * 16] = row_start[node];
  }
}

// Phase A: partition edges into dst-buckets (writes dense within bucket)
__global__ __launch_bounds__(256) void k_bucket(const int* __restrict__ src,
                                                const int* __restrict__ dst,
                                                int* __restrict__ bcur,
                                                uint2* __restrict__ bkt, int E) {
  int e = blockIdx.x * 256 + threadIdx.x;
  if (e >= E) return;
  int d = dst[e];
  int pos = atomicAdd(&bcur[(d >> BKT_SHIFT) * 16], 1);
  bkt[pos] = make_uint2((uint)src[e], (uint)d);
}

// Phase B: one block per bucket; LDS cursors; col writes land in a ~8KB window
__global__ __launch_bounds__(256) void k_fill2(const uint2* __restrict__ bkt,
                                               const int* __restrict__ row_start,
                                               int* __restrict__ col, int n) {
  __shared__ int cur[BKT_NODES];
  int base = blockIdx.x << BKT_SHIFT;
  int t = threadIdx.x;
  int top = min(base + BKT_NODES, n);
  if (t < BKT_NODES && base + t < n) cur[t] = row_start[base + t];
  __syncthreads();
  int ebeg = row_start[base];
  int eend = row_start[top];
  for (int j = ebeg + t; j < eend; j += 256) {
    uint2 e = bkt[j];
    int pos = atomicAdd(&cur[(int)e.y - base], 1);
    col[pos] = (int)e.x;
  }
}

// ---------------- gather-mean (bf16 in/out, fp32 accum) ----------------
// one wave per node; lane l owns features [2l, 2l+1] (one dword)
__global__ __launch_bounds__(256) void k_aggr_bf(const ushort* __restrict__ h,
                                                 const int* __restrict__ row_start,
                                                 const int* __restrict__ col,
                                                 ushort* __restrict__ aggr, int n) {
  int gw = (blockIdx.x * 256 + threadIdx.x) >> 6;
  int lane = threadIdx.x & 63;
  if (gw >= n) return;
  int beg = row_start[gw], end = row_start[gw + 1];
  float ax = 0.f, ay = 0.f;
  int j = beg;
  for (; j + 4 <= end; j += 4) {
    uint v0 = *(const uint*)&h[(size_t)col[j]     * NF + lane * 2];
    uint v1 = *(const uint*)&h[(size_t)col[j + 1] * NF + lane * 2];
    uint v2 = *(const uint*)&h[(size_t)col[j + 2] * NF + lane * 2];
    uint v3 = *(const uint*)&h[(size_t)col[j + 3] * NF + lane * 2];
    ax += __uint_as_float(v0 << 16) + __uint_as_float(v1 << 16) +
          __uint_as_float(v2 << 16) + __uint_as_float(v3 << 16);
    ay += __uint_as_float(v0 & 0xffff0000u) + __uint_as_float(v1 & 0xffff0000u) +
          __uint_as_float(v2 & 0xffff0000u) + __uint_as_float(v3 & 0xffff0000u);
  }
  for (; j < end; j++) {
    uint v0 = *(const uint*)&h[(size_t)col[j] * NF + lane * 2];
    ax += __uint_as_float(v0 << 16);
    ay += __uint_as_float(v0 & 0xffff0000u);
  }
  int d = end - beg;
  float inv = (d > 0) ? 1.0f / (float)d : 0.0f;
  uint o = (uint)f2bf(ax * inv) | ((uint)f2bf(ay * inv) << 16);
  *(uint*)&aggr[(size_t)gw * NF + lane * 2] = o;
}

// ---------------- MFMA GEMM: hout = relu([aggr|hin] @ [Wl;Wr] + b) ----------------
#define WSWZ(c, kbyte) (((c) << 9) + ((kbyte) ^ (((c) & 7) << 4)))

__global__ __launch_bounds__(256) void k_gemm_mfma(const ushort* __restrict__ aggr,
                                                   const ushort* __restrict__ hin,
                                                   ushort* __restrict__ hout,
                                                   const float* __restrict__ Wl,
                                                   const float* __restrict__ Wr,
                                                   const float* __restrict__ bias,
                                                   int n, int nslab) {
  __shared__ ushort Wt[128 * 256];   // [col][k] bf16, 64 KB, XOR-swizzled
  int t = threadIdx.x;
  for (int i = t; i < 128 * 128; i += 256) {
    int k = i >> 7, c = i & 127;
    *(ushort*)((char*)Wt + WSWZ(c, k * 2))         = f2bf(Wl[i]);
    *(ushort*)((char*)Wt + WSWZ(c, (k + 128) * 2)) = f2bf(Wr[i]);
  }
  __syncthreads();

  int wv = t >> 6, lane = t & 63;
  int c0 = wv * 32;
  int lrow = lane & 15, lhi = lane >> 4;

  bf16x8 bfrag[8][2];
  #pragma unroll
  for (int kc = 0; kc < 8; kc++)
    #pragma unroll
    for (int ct = 0; ct < 2; ct++) {
      int colv = c0 + ct * 16 + lrow;
      int kbyte = (kc * 32 + lhi * 8) * 2;
      bfrag[kc][ct] = *(const bf16x8*)((const char*)Wt + WSWZ(colv, kbyte));
    }
  float bv0 = bias[c0 + lrow], bv1 = bias[c0 + 16 + lrow];

  for (int sl = blockIdx.x; sl < nslab; sl += GEMM_BLOCKS) {
    int row0 = sl * 64;
    f32x4 acc[4][2];
    #pragma unroll
    for (int rt = 0; rt < 4; rt++)
      #pragma unroll
      for (int ct = 0; ct < 2; ct++) acc[rt][ct] = (f32x4){0.f, 0.f, 0.f, 0.f};

    #pragma unroll
    for (int kc = 0; kc < 8; kc++) {
      const ushort* Asrc = (kc < 4) ? aggr : hin;
      int k0 = (kc & 3) * 32 + lhi * 8;
      bf16x8 af[4];
      #pragma unroll
      for (int rt = 0; rt < 4; rt++) {
        int r = row0 + rt * 16 + lrow;
        if (r >= n) r = n - 1;
        af[rt] = *(const bf16x8*)&Asrc[(size_t)r * NF + k0];
      }
      #pragma unroll
      for (int rt = 0; rt < 4; rt++) {
        acc[rt][0] = __builtin_amdgcn_mfma_f32_16x16x32_bf16(af[rt], bfrag[kc][0], acc[rt][0], 0, 0, 0);
        acc[rt][1] = __builtin_amdgcn_mfma_f32_16x16x32_bf16(af[rt], bfrag[kc][1], acc[rt][1], 0, 0, 0);
      }
    }
    // C/D: col = lane&15, row = (lane>>4)*4 + reg   [m89-verified]
    #pragma unroll
    for (int rt = 0; rt < 4; rt++) {
      int rbase = row0 + rt * 16 + lhi * 4;
      #pragma unroll
      for (int r = 0; r < 4; r++) {
        int row = rbase + r;
        if (row < n) {
          hout[(size_t)row * NF + c0 + lrow]      = f2bf(fmaxf(acc[rt][0][r] + bv0, 0.f));
          hout[(size_t)row * NF + c0 + 16 + lrow] = f2bf(fmaxf(acc[rt][1][r] + bv1, 0.f));
        }
      }
    }
  }
}

// ---------------- pool + head ----------------
__global__ __launch_bounds__(128) void k_pool1(const ushort* __restrict__ h,
                                               float* __restrict__ partial, int n) {
  int f = threadIdx.x;
  float s = 0.f;
  for (int r = blockIdx.x; r < n; r += PB) s += b2f(h[(size_t)r * NF + f]);
  partial[blockIdx.x * NF + f] = s;
}

__global__ __launch_bounds__(128) void k_pool2(const float* __restrict__ partial,
                                               const float* __restrict__ Wg,
                                               const float* __restrict__ bg,
                                               float* __restrict__ out, int n) {
  __shared__ float g[NF];
  int f = threadIdx.x;
  float s = 0.f;
  for (int b = 0; b < PB; b++) s += partial[b * NF + f];
  g[f] = s / (float)n;
  __syncthreads();
  if (f < 64) {
    float z = bg[f];
    #pragma unroll 4
    for (int k = 0; k < NF; k++) z += g[k] * Wg[k * 64 + f];
    out[f] = 1.0f / (1.0f + expf(-z));
  }
}

// ---------------- launch ----------------
extern "C" void kernel_launch(void* const* d_in, const int* in_sizes, int n_in,
                              void* d_out, int out_size, void* d_ws, size_t ws_size,
                              hipStream_t stream) {
  const float* x   = (const float*)d_in[0];
  const int*   ei  = (const int*)d_in[1];
  const float* Wl1 = (const float*)d_in[2];
  const float* Wr1 = (const float*)d_in[3];
  const float* b1  = (const float*)d_in[4];
  const float* Wl2 = (const float*)d_in[5];
  const float* Wr2 = (const float*)d_in[6];
  const float* b2  = (const float*)d_in[7];
  const float* Wl3 = (const float*)d_in[8];
  const float* Wr3 = (const float*)d_in[9];
  const float* b3  = (const float*)d_in[10];
  const float* Wg  = (const float*)d_in[11];
  const float* bg  = (const float*)d_in[12];
  float* out = (float*)d_out;

  int n = in_sizes[0] / NF;      // 100000
  int E = in_sizes[1] / 2;       // 1600000
  const int* srcp = ei;
  const int* dstp = ei + E;

  char* w = (char*)d_ws;
  size_t off = 0;
  auto carve = [&](size_t bytes) -> void* {
    off = (off + 255) & ~(size_t)255;
    void* p = w + off;
    off += bytes;
    return p;
  };
  int nb = (n + SCAN_COVER - 1) / SCAN_COVER;
  int nbkt = (n + BKT_NODES - 1) / BKT_NODES;   // 782 buckets
  int*    col       = (int*)   carve((size_t)E * 4);
  int*    row_start = (int*)   carve((size_t)(n + 1) * 4);
  int*    deg       = (int*)   carve((size_t)n * 4);
  int*    bsum      = (int*)   carve((size_t)nb * 4);
  int*    bcur      = (int*)   carve((size_t)nbkt * 64);   // 1 cursor / 64B line
  ushort* xb        = (ushort*)carve((size_t)n * NF * 2);
  ushort* aggr      = (ushort*)carve((size_t)n * NF * 2);
  ushort* ha        = (ushort*)carve((size_t)n * NF * 2);
  ushort* hb        = (ushort*)carve((size_t)n * NF * 2);
  float*  partial   = (float*) carve((size_t)PB * NF * 4);
  uint2*  bkt       = (uint2*)hb;   // staging aliases hb (dead until layer 2)

  int eg = (E + 255) / 256;
  int ag = (n + 3) / 4;
  int nslab = (n + 63) / 64;

  // convert x to bf16
  k_cvt<<<2048, 256, 0, stream>>>(x, xb, n * NF / 4);

  // CSR build: count -> scan -> bucket -> local fill
  hipMemsetAsync(deg, 0, (size_t)n * 4, stream);
  k_count<<<eg, 256, 0, stream>>>(dstp, deg, E);
  k_scan1<<<nb, 256, 0, stream>>>(deg, bsum, n);
  k_scan2<<<1, 128, 0, stream>>>(bsum, row_start, nb, n);
  k_scan3<<<nb, 256, 0, stream>>>(deg, bsum, row_start, n);
  k_bcur_init<<<(nbkt + 255) / 256, 256, 0, stream>>>(row_start, bcur, nbkt, n);
  k_bucket<<<eg, 256, 0, stream>>>(srcp, dstp, bcur, bkt, E);
  k_fill2<<<nbkt, 256, 0, stream>>>(bkt, row_start, col, n);

  // layer 1: xb -> ha
  k_aggr_bf<<<ag, 256, 0, stream>>>(xb, row_start, col, aggr, n);
  k_gemm_mfma<<<GEMM_BLOCKS, 256, 0, stream>>>(aggr, xb, ha, Wl1, Wr1, b1, n, nslab);
  // layer 2: ha -> hb
  k_aggr_bf<<<ag, 256, 0, stream>>>(ha, row_start, col, aggr, n);
  k_gemm_mfma<<<GEMM_BLOCKS, 256, 0, stream>>>(aggr, ha, hb, Wl2, Wr2, b2, n, nslab);
  // layer 3: hb -> ha
  k_aggr_bf<<<ag, 256, 0, stream>>>(hb, row_start, col, aggr, n);
  k_gemm_mfma<<<GEMM_BLOCKS, 256, 0, stream>>>(aggr, hb, ha, Wl3, Wr3, b3, n, nslab);

  // pool + head
  k_pool1<<<PB, 128, 0, stream>>>(ha, partial, n);
  k_pool2<<<1, 128, 0, stream>>>(partial, Wg, bg, out, n);
}

// Round 6
// 659.263 us; speedup vs baseline: 1.7505x; 1.1120x over previous
//
#include <hip/hip_runtime.h>
#include <hip/hip_bf16.h>

#define NF 128   // feature dim
#define PB 512   // pool partial blocks
#define SCAN_COVER 1024  // elems per scan block (256 thr x 4)
#define GEMM_BLOCKS 512  // persistent-ish gemm grid
#define PART_SHIFT 9     // 512 nodes per coarse bucket
#define PART_NODES 512
#define PART_CHUNK 4096  // edges per partition block (256 thr x 16)

typedef __attribute__((ext_vector_type(8))) short bf16x8;
typedef __attribute__((ext_vector_type(4))) float f32x4;

__device__ inline float b2f(ushort u) { return __uint_as_float(((uint)u) << 16); }
__device__ inline ushort f2bf(float f) {           // round-to-nearest-even
  uint u = __float_as_uint(f);
  return (ushort)((u + 0x7fffu + ((u >> 16) & 1u)) >> 16);
}

// ---------------- x -> bf16 ----------------
__global__ __launch_bounds__(256) void k_cvt(const float* __restrict__ x,
                                             ushort* __restrict__ xb, int total4) {
  for (int i = blockIdx.x * 256 + threadIdx.x; i < total4; i += gridDim.x * 256) {
    float4 v = *(const float4*)&x[(size_t)i * 4];
    ushort4 o;
    o.x = f2bf(v.x); o.y = f2bf(v.y); o.z = f2bf(v.z); o.w = f2bf(v.w);
    *(ushort4*)&xb[(size_t)i * 4] = o;
  }
}

// ---------------- CSR build ----------------
__global__ __launch_bounds__(256) void k_count(const int* __restrict__ dst,
                                               int* __restrict__ deg, int E) {
  int e = blockIdx.x * 256 + threadIdx.x;
  if (e < E) atomicAdd(&deg[dst[e]], 1);
}

__global__ __launch_bounds__(256) void k_scan1(const int* __restrict__ deg,
                                               int* __restrict__ bsum, int n) {
  __shared__ int s[256];
  int t = threadIdx.x;
  int base = blockIdx.x * SCAN_COVER + t * 4;
  int sum = 0;
  #pragma unroll
  for (int i = 0; i < 4; i++) { int idx = base + i; if (idx < n) sum += deg[idx]; }
  s[t] = sum;
  __syncthreads();
  for (int off = 128; off > 0; off >>= 1) {
    if (t < off) s[t] += s[t + off];
    __syncthreads();
  }
  if (t == 0) bsum[blockIdx.x] = s[0];
}

__global__ __launch_bounds__(128) void k_scan2(int* __restrict__ bsum,
                                               int* __restrict__ row_start,
                                               int nb, int n) {
  __shared__ int s[128];
  int t = threadIdx.x;
  int v = (t < nb) ? bsum[t] : 0;
  s[t] = v;
  __syncthreads();
  for (int off = 1; off < 128; off <<= 1) {
    int u = (t >= off) ? s[t - off] : 0;
    __syncthreads();
    s[t] += u;
    __syncthreads();
  }
  if (t < nb) bsum[t] = s[t] - v;          // exclusive block prefix
  if (t == 127) row_start[n] = s[127];
}

__global__ __launch_bounds__(256) void k_scan3(const int* __restrict__ deg,
                                               const int* __restrict__ bsum,
                                               int* __restrict__ row_start, int n) {
  __shared__ int s[256];
  int t = threadIdx.x;
  int base = blockIdx.x * SCAN_COVER + t * 4;
  int d[4];
  int sum = 0;
  #pragma unroll
  for (int i = 0; i < 4; i++) {
    int idx = base + i;
    d[i] = (idx < n) ? deg[idx] : 0;
    sum += d[i];
  }
  s[t] = sum;
  __syncthreads();
  for (int off = 1; off < 256; off <<= 1) {
    int u = (t >= off) ? s[t - off] : 0;
    __syncthreads();
    s[t] += u;
    __syncthreads();
  }
  int pre = s[t] - sum + bsum[blockIdx.x];
  #pragma unroll
  for (int i = 0; i < 4; i++) {
    int idx = base + i;
    if (idx < n) row_start[idx] = pre;
    pre += d[i];
  }
}

__global__ __launch_bounds__(256) void k_gcur_init(const int* __restrict__ row_start,
                                                   int* __restrict__ gcur, int nbkt) {
  int b = blockIdx.x * 256 + threadIdx.x;
  if (b < nbkt) gcur[b] = row_start[b << PART_SHIFT];
}

// LDS-ranked partition: block reserves contiguous runs per bucket -> each 64B
// line of bkt written by ONE block (one XCD); records packed to 4B.
__global__ __launch_bounds__(256) void k_part(const int* __restrict__ src,
                                              const int* __restrict__ dst,
                                              int* __restrict__ gcur,
                                              uint* __restrict__ bkt, int E) {
  __shared__ int lhist[256];
  __shared__ int lbase[256];
  int t = threadIdx.x;
  int cb = blockIdx.x * PART_CHUNK;
  lhist[t] = 0;
  __syncthreads();
  uint rec[16];
  short rb[16];
  short rr[16];
  #pragma unroll
  for (int i = 0; i < 16; i++) {
    int e = cb + i * 256 + t;
    if (e < E) {
      int s = src[e], d = dst[e];
      int b = d >> PART_SHIFT;
      rec[i] = ((uint)(d & (PART_NODES - 1)) << 17) | (uint)s;
      rb[i] = (short)b;
      rr[i] = (short)atomicAdd(&lhist[b], 1);
    } else rb[i] = -1;
  }
  __syncthreads();
  int c = lhist[t];
  lbase[t] = (c > 0) ? atomicAdd(&gcur[t], c) : 0;
  __syncthreads();
  #pragma unroll
  for (int i = 0; i < 16; i++) {
    if (rb[i] >= 0) bkt[lbase[rb[i]] + (int)rr[i]] = rec[i];
  }
}

// fine fill: one block per 512-node bucket; LDS cursors; col writes in a
// contiguous per-block window (single-XCD write combining)
__global__ __launch_bounds__(256) void k_fill3(const uint* __restrict__ bkt,
                                               const int* __restrict__ row_start,
                                               int* __restrict__ col, int n) {
  __shared__ int cur[PART_NODES];
  int base = blockIdx.x << PART_SHIFT;
  int t = threadIdx.x;
  int top = min(base + PART_NODES, n);
  for (int i = t; i < top - base; i += 256) cur[i] = row_start[base + i];
  __syncthreads();
  int ebeg = row_start[base], eend = row_start[top];
  for (int j = ebeg + t; j < eend; j += 256) {
    uint r = bkt[j];
    int pos = atomicAdd(&cur[r >> 17], 1);
    col[pos] = (int)(r & 0x1FFFFu);
  }
}

// ---------------- gather-mean (bf16 in/out, fp32 accum) ----------------
// one wave per node; lane l owns features [2l, 2l+1] (one dword)
__global__ __launch_bounds__(256) void k_aggr_bf(const ushort* __restrict__ h,
                                                 const int* __restrict__ row_start,
                                                 const int* __restrict__ col,
                                                 ushort* __restrict__ aggr, int n) {
  int gw = (blockIdx.x * 256 + threadIdx.x) >> 6;
  int lane = threadIdx.x & 63;
  if (gw >= n) return;
  int beg = row_start[gw], end = row_start[gw + 1];
  float ax = 0.f, ay = 0.f;
  int j = beg;
  for (; j + 4 <= end; j += 4) {
    uint v0 = *(const uint*)&h[(size_t)col[j]     * NF + lane * 2];
    uint v1 = *(const uint*)&h[(size_t)col[j + 1] * NF + lane * 2];
    uint v2 = *(const uint*)&h[(size_t)col[j + 2] * NF + lane * 2];
    uint v3 = *(const uint*)&h[(size_t)col[j + 3] * NF + lane * 2];
    ax += __uint_as_float(v0 << 16) + __uint_as_float(v1 << 16) +
          __uint_as_float(v2 << 16) + __uint_as_float(v3 << 16);
    ay += __uint_as_float(v0 & 0xffff0000u) + __uint_as_float(v1 & 0xffff0000u) +
          __uint_as_float(v2 & 0xffff0000u) + __uint_as_float(v3 & 0xffff0000u);
  }
  for (; j < end; j++) {
    uint v0 = *(const uint*)&h[(size_t)col[j] * NF + lane * 2];
    ax += __uint_as_float(v0 << 16);
    ay += __uint_as_float(v0 & 0xffff0000u);
  }
  int d = end - beg;
  float inv = (d > 0) ? 1.0f / (float)d : 0.0f;
  uint o = (uint)f2bf(ax * inv) | ((uint)f2bf(ay * inv) << 16);
  *(uint*)&aggr[(size_t)gw * NF + lane * 2] = o;
}

// ---------------- MFMA GEMM: hout = relu([aggr|hin] @ [Wl;Wr] + b) ----------------
#define WSWZ(c, kbyte) (((c) << 9) + ((kbyte) ^ (((c) & 7) << 4)))

__global__ __launch_bounds__(256) void k_gemm_mfma(const ushort* __restrict__ aggr,
                                                   const ushort* __restrict__ hin,
                                                   ushort* __restrict__ hout,
                                                   const float* __restrict__ Wl,
                                                   const float* __restrict__ Wr,
                                                   const float* __restrict__ bias,
                                                   int n, int nslab) {
  __shared__ ushort Wt[128 * 256];   // [col][k] bf16, 64 KB, XOR-swizzled
  int t = threadIdx.x;
  for (int i = t; i < 128 * 128; i += 256) {
    int k = i >> 7, c = i & 127;
    *(ushort*)((char*)Wt + WSWZ(c, k * 2))         = f2bf(Wl[i]);
    *(ushort*)((char*)Wt + WSWZ(c, (k + 128) * 2)) = f2bf(Wr[i]);
  }
  __syncthreads();

  int wv = t >> 6, lane = t & 63;
  int c0 = wv * 32;
  int lrow = lane & 15, lhi = lane >> 4;

  bf16x8 bfrag[8][2];
  #pragma unroll
  for (int kc = 0; kc < 8; kc++)
    #pragma unroll
    for (int ct = 0; ct < 2; ct++) {
      int colv = c0 + ct * 16 + lrow;
      int kbyte = (kc * 32 + lhi * 8) * 2;
      bfrag[kc][ct] = *(const bf16x8*)((const char*)Wt + WSWZ(colv, kbyte));
    }
  float bv0 = bias[c0 + lrow], bv1 = bias[c0 + 16 + lrow];

  for (int sl = blockIdx.x; sl < nslab; sl += GEMM_BLOCKS) {
    int row0 = sl * 64;
    f32x4 acc[4][2];
    #pragma unroll
    for (int rt = 0; rt < 4; rt++)
      #pragma unroll
      for (int ct = 0; ct < 2; ct++) acc[rt][ct] = (f32x4){0.f, 0.f, 0.f, 0.f};

    #pragma unroll
    for (int kc = 0; kc < 8; kc++) {
      const ushort* Asrc = (kc < 4) ? aggr : hin;
      int k0 = (kc & 3) * 32 + lhi * 8;
      bf16x8 af[4];
      #pragma unroll
      for (int rt = 0; rt < 4; rt++) {
        int r = row0 + rt * 16 + lrow;
        if (r >= n) r = n - 1;
        af[rt] = *(const bf16x8*)&Asrc[(size_t)r * NF + k0];
      }
      #pragma unroll
      for (int rt = 0; rt < 4; rt++) {
        acc[rt][0] = __builtin_amdgcn_mfma_f32_16x16x32_bf16(af[rt], bfrag[kc][0], acc[rt][0], 0, 0, 0);
        acc[rt][1] = __builtin_amdgcn_mfma_f32_16x16x32_bf16(af[rt], bfrag[kc][1], acc[rt][1], 0, 0, 0);
      }
    }
    // C/D: col = lane&15, row = (lane>>4)*4 + reg   [m89-verified]
    #pragma unroll
    for (int rt = 0; rt < 4; rt++) {
      int rbase = row0 + rt * 16 + lhi * 4;
      #pragma unroll
      for (int r = 0; r < 4; r++) {
        int row = rbase + r;
        if (row < n) {
          hout[(size_t)row * NF + c0 + lrow]      = f2bf(fmaxf(acc[rt][0][r] + bv0, 0.f));
          hout[(size_t)row * NF + c0 + 16 + lrow] = f2bf(fmaxf(acc[rt][1][r] + bv1, 0.f));
        }
      }
    }
  }
}

// ---------------- pool + head ----------------
__global__ __launch_bounds__(128) void k_pool1(const ushort* __restrict__ h,
                                               float* __restrict__ partial, int n) {
  int f = threadIdx.x;
  float s = 0.f;
  for (int r = blockIdx.x; r < n; r += PB) s += b2f(h[(size_t)r * NF + f]);
  partial[blockIdx.x * NF + f] = s;
}

__global__ __launch_bounds__(128) void k_pool2(const float* __restrict__ partial,
                                               const float* __restrict__ Wg,
                                               const float* __restrict__ bg,
                                               float* __restrict__ out, int n) {
  __shared__ float g[NF];
  int f = threadIdx.x;
  float s = 0.f;
  for (int b = 0; b < PB; b++) s += partial[b * NF + f];
  g[f] = s / (float)n;
  __syncthreads();
  if (f < 64) {
    float z = bg[f];
    #pragma unroll 4
    for (int k = 0; k < NF; k++) z += g[k] * Wg[k * 64 + f];
    out[f] = 1.0f / (1.0f + expf(-z));
  }
}

// ---------------- launch ----------------
extern "C" void kernel_launch(void* const* d_in, const int* in_sizes, int n_in,
                              void* d_out, int out_size, void* d_ws, size_t ws_size,
                              hipStream_t stream) {
  const float* x   = (const float*)d_in[0];
  const int*   ei  = (const int*)d_in[1];
  const float* Wl1 = (const float*)d_in[2];
  const float* Wr1 = (const float*)d_in[3];
  const float* b1  = (const float*)d_in[4];
  const float* Wl2 = (const float*)d_in[5];
  const float* Wr2 = (const float*)d_in[6];
  const float* b2  = (const float*)d_in[7];
  const float* Wl3 = (const float*)d_in[8];
  const float* Wr3 = (const float*)d_in[9];
  const float* b3  = (const float*)d_in[10];
  const float* Wg  = (const float*)d_in[11];
  const float* bg  = (const float*)d_in[12];
  float* out = (float*)d_out;

  int n = in_sizes[0] / NF;      // 100000
  int E = in_sizes[1] / 2;       // 1600000
  const int* srcp = ei;
  const int* dstp = ei + E;

  char* w = (char*)d_ws;
  size_t off = 0;
  auto carve = [&](size_t bytes) -> void* {
    off = (off + 255) & ~(size_t)255;
    void* p = w + off;
    off += bytes;
    return p;
  };
  int nb = (n + SCAN_COVER - 1) / SCAN_COVER;
  int nbkt = (n + PART_NODES - 1) / PART_NODES;   // 196 coarse buckets
  int*    col       = (int*)   carve((size_t)E * 4);
  int*    row_start = (int*)   carve((size_t)(n + 1) * 4);
  int*    deg       = (int*)   carve((size_t)n * 4);
  int*    bsum      = (int*)   carve((size_t)nb * 4);
  int*    gcur      = (int*)   carve((size_t)256 * 4);
  ushort* xb        = (ushort*)carve((size_t)n * NF * 2);
  ushort* aggr      = (ushort*)carve((size_t)n * NF * 2);
  ushort* ha        = (ushort*)carve((size_t)n * NF * 2);
  ushort* hb        = (ushort*)carve((size_t)n * NF * 2);
  float*  partial   = (float*) carve((size_t)PB * NF * 4);
  uint*   bkt       = (uint*)hb;   // 4B-packed staging aliases hb (dead until layer 2)

  int eg = (E + 255) / 256;
  int ag = (n + 3) / 4;
  int nslab = (n + 63) / 64;
  int npart = (E + PART_CHUNK - 1) / PART_CHUNK;  // 391 partition blocks

  // convert x to bf16
  k_cvt<<<2048, 256, 0, stream>>>(x, xb, n * NF / 4);

  // CSR build: count -> scan -> block-reserved partition -> local fill
  hipMemsetAsync(deg, 0, (size_t)n * 4, stream);
  k_count<<<eg, 256, 0, stream>>>(dstp, deg, E);
  k_scan1<<<nb, 256, 0, stream>>>(deg, bsum, n);
  k_scan2<<<1, 128, 0, stream>>>(bsum, row_start, nb, n);
  k_scan3<<<nb, 256, 0, stream>>>(deg, bsum, row_start, n);
  k_gcur_init<<<1, 256, 0, stream>>>(row_start, gcur, nbkt);
  k_part<<<npart, 256, 0, stream>>>(srcp, dstp, gcur, bkt, E);
  k_fill3<<<nbkt, 256, 0, stream>>>(bkt, row_start, col, n);

  // layer 1: xb -> ha
  k_aggr_bf<<<ag, 256, 0, stream>>>(xb, row_start, col, aggr, n);
  k_gemm_mfma<<<GEMM_BLOCKS, 256, 0, stream>>>(aggr, xb, ha, Wl1, Wr1, b1, n, nslab);
  // layer 2: ha -> hb
  k_aggr_bf<<<ag, 256, 0, stream>>>(ha, row_start, col, aggr, n);
  k_gemm_mfma<<<GEMM_BLOCKS, 256, 0, stream>>>(aggr, ha, hb, Wl2, Wr2, b2, n, nslab);
  // layer 3: hb -> ha
  k_aggr_bf<<<ag, 256, 0, stream>>>(hb, row_start, col, aggr, n);
  k_gemm_mfma<<<GEMM_BLOCKS, 256, 0, stream>>>(aggr, hb, ha, Wl3, Wr3, b3, n, nslab);

  // pool + head
  k_pool1<<<PB, 128, 0, stream>>>(ha, partial, n);
  k_pool2<<<1, 128, 0, stream>>>(partial, Wg, bg, out, n);
}

// Round 7
// 628.452 us; speedup vs baseline: 1.8363x; 1.0490x over previous
//
#include <hip/hip_runtime.h>
#include <hip/hip_bf16.h>

#define NF 128   // feature dim
#define PB 512   // pool partial blocks
#define SCAN_COVER 1024  // elems per scan block (256 thr x 4)
#define GEMM_BLOCKS 512  // persistent-ish gemm grid
#define PART_SHIFT 9     // 512 nodes per coarse bucket
#define PART_NODES 512
#define PART_CHUNK 4096  // edges per partition block (256 thr x 16)

typedef __attribute__((ext_vector_type(8))) short bf16x8;
typedef __attribute__((ext_vector_type(4))) float f32x4;

__device__ inline float b2f(ushort u) { return __uint_as_float(((uint)u) << 16); }
__device__ inline ushort f2bf(float f) {           // round-to-nearest-even
  uint u = __float_as_uint(f);
  return (ushort)((u + 0x7fffu + ((u >> 16) & 1u)) >> 16);
}

// ---------------- x -> bf16 ----------------
__global__ __launch_bounds__(256) void k_cvt(const float* __restrict__ x,
                                             ushort* __restrict__ xb, int total4) {
  for (int i = blockIdx.x * 256 + threadIdx.x; i < total4; i += gridDim.x * 256) {
    float4 v = *(const float4*)&x[(size_t)i * 4];
    ushort4 o;
    o.x = f2bf(v.x); o.y = f2bf(v.y); o.z = f2bf(v.z); o.w = f2bf(v.w);
    *(ushort4*)&xb[(size_t)i * 4] = o;
  }
}

// ---------------- CSR build ----------------
__global__ __launch_bounds__(256) void k_count(const int* __restrict__ dst,
                                               int* __restrict__ deg, int E) {
  int e = blockIdx.x * 256 + threadIdx.x;
  if (e < E) atomicAdd(&deg[dst[e]], 1);
}

__global__ __launch_bounds__(256) void k_scan1(const int* __restrict__ deg,
                                               int* __restrict__ bsum, int n) {
  __shared__ int s[256];
  int t = threadIdx.x;
  int base = blockIdx.x * SCAN_COVER + t * 4;
  int sum = 0;
  #pragma unroll
  for (int i = 0; i < 4; i++) { int idx = base + i; if (idx < n) sum += deg[idx]; }
  s[t] = sum;
  __syncthreads();
  for (int off = 128; off > 0; off >>= 1) {
    if (t < off) s[t] += s[t + off];
    __syncthreads();
  }
  if (t == 0) bsum[blockIdx.x] = s[0];
}

__global__ __launch_bounds__(128) void k_scan2(int* __restrict__ bsum,
                                               int* __restrict__ row_start,
                                               int nb, int n) {
  __shared__ int s[128];
  int t = threadIdx.x;
  int v = (t < nb) ? bsum[t] : 0;
  s[t] = v;
  __syncthreads();
  for (int off = 1; off < 128; off <<= 1) {
    int u = (t >= off) ? s[t - off] : 0;
    __syncthreads();
    s[t] += u;
    __syncthreads();
  }
  if (t < nb) bsum[t] = s[t] - v;          // exclusive block prefix
  if (t == 127) row_start[n] = s[127];
}

__global__ __launch_bounds__(256) void k_scan3(const int* __restrict__ deg,
                                               const int* __restrict__ bsum,
                                               int* __restrict__ row_start, int n) {
  __shared__ int s[256];
  int t = threadIdx.x;
  int base = blockIdx.x * SCAN_COVER + t * 4;
  int d[4];
  int sum = 0;
  #pragma unroll
  for (int i = 0; i < 4; i++) {
    int idx = base + i;
    d[i] = (idx < n) ? deg[idx] : 0;
    sum += d[i];
  }
  s[t] = sum;
  __syncthreads();
  for (int off = 1; off < 256; off <<= 1) {
    int u = (t >= off) ? s[t - off] : 0;
    __syncthreads();
    s[t] += u;
    __syncthreads();
  }
  int pre = s[t] - sum + bsum[blockIdx.x];
  #pragma unroll
  for (int i = 0; i < 4; i++) {
    int idx = base + i;
    if (idx < n) row_start[idx] = pre;
    pre += d[i];
  }
}

__global__ __launch_bounds__(256) void k_gcur_init(const int* __restrict__ row_start,
                                                   int* __restrict__ gcur, int nbkt) {
  int b = blockIdx.x * 256 + threadIdx.x;
  if (b < nbkt) gcur[b] = row_start[b << PART_SHIFT];
}

// LDS-ranked partition: block reserves contiguous runs per bucket -> each 64B
// line of bkt written by ONE block (one XCD); records packed to 4B.
__global__ __launch_bounds__(256) void k_part(const int* __restrict__ src,
                                              const int* __restrict__ dst,
                                              int* __restrict__ gcur,
                                              uint* __restrict__ bkt, int E) {
  __shared__ int lhist[256];
  __shared__ int lbase[256];
  int t = threadIdx.x;
  int cb = blockIdx.x * PART_CHUNK;
  lhist[t] = 0;
  __syncthreads();
  uint rec[16];
  short rb[16];
  short rr[16];
  #pragma unroll
  for (int i = 0; i < 16; i++) {
    int e = cb + i * 256 + t;
    if (e < E) {
      int s = src[e], d = dst[e];
      int b = d >> PART_SHIFT;
      rec[i] = ((uint)(d & (PART_NODES - 1)) << 17) | (uint)s;
      rb[i] = (short)b;
      rr[i] = (short)atomicAdd(&lhist[b], 1);
    } else rb[i] = -1;
  }
  __syncthreads();
  int c = lhist[t];
  lbase[t] = (c > 0) ? atomicAdd(&gcur[t], c) : 0;
  __syncthreads();
  #pragma unroll
  for (int i = 0; i < 16; i++) {
    if (rb[i] >= 0) bkt[lbase[rb[i]] + (int)rr[i]] = rec[i];
  }
}

// fine fill: one block per 512-node bucket; LDS cursors; col writes in a
// contiguous per-block window (single-XCD write combining)
__global__ __launch_bounds__(256) void k_fill3(const uint* __restrict__ bkt,
                                               const int* __restrict__ row_start,
                                               int* __restrict__ col, int n) {
  __shared__ int cur[PART_NODES];
  int base = blockIdx.x << PART_SHIFT;
  int t = threadIdx.x;
  int top = min(base + PART_NODES, n);
  for (int i = t; i < top - base; i += 256) cur[i] = row_start[base + i];
  __syncthreads();
  int ebeg = row_start[base], eend = row_start[top];
  for (int j = ebeg + t; j < eend; j += 256) {
    uint r = bkt[j];
    int pos = atomicAdd(&cur[r >> 17], 1);
    col[pos] = (int)(r & 0x1FFFFu);
  }
}

// ---------------- gather-mean (bf16 in/out, fp32 accum) ----------------
// one wave per node; lane-split: half h (lane>>5) handles edges 2i+h, each
// lane owns 4 feats (8B loads -> 512B per instr across the wave); col indices
// prefetched 64-at-a-time and broadcast via shfl; 8 edges in flight.
__global__ __launch_bounds__(256) void k_aggr_bf(const ushort* __restrict__ h,
                                                 const int* __restrict__ row_start,
                                                 const int* __restrict__ col,
                                                 ushort* __restrict__ aggr, int n) {
  int gw = (blockIdx.x * 256 + threadIdx.x) >> 6;
  int lane = threadIdx.x & 63;
  if (gw >= n) return;
  int beg = row_start[gw], end = row_start[gw + 1];
  int half = lane >> 5, sl = lane & 31;
  const ushort* hbase = h + (size_t)sl * 4;
  float a0 = 0.f, a1 = 0.f, a2 = 0.f, a3 = 0.f;

  for (int cb = beg; cb < end; cb += 64) {
    int idx = cb + lane;
    int cv = (idx < end) ? col[idx] : 0;
    int m = min(64, end - cb);
    int j = 0;
    for (; j + 8 <= m; j += 8) {         // 4 pairs (8 edges) in flight
      uint2 v0, v1, v2, v3;
      int s0 = __shfl(cv, j + 0 + half);
      int s1 = __shfl(cv, j + 2 + half);
      int s2 = __shfl(cv, j + 4 + half);
      int s3 = __shfl(cv, j + 6 + half);
      v0 = *(const uint2*)&hbase[(size_t)s0 * NF];
      v1 = *(const uint2*)&hbase[(size_t)s1 * NF];
      v2 = *(const uint2*)&hbase[(size_t)s2 * NF];
      v3 = *(const uint2*)&hbase[(size_t)s3 * NF];
      a0 += __uint_as_float(v0.x << 16) + __uint_as_float(v1.x << 16) +
            __uint_as_float(v2.x << 16) + __uint_as_float(v3.x << 16);
      a1 += __uint_as_float(v0.x & 0xffff0000u) + __uint_as_float(v1.x & 0xffff0000u) +
            __uint_as_float(v2.x & 0xffff0000u) + __uint_as_float(v3.x & 0xffff0000u);
      a2 += __uint_as_float(v0.y << 16) + __uint_as_float(v1.y << 16) +
            __uint_as_float(v2.y << 16) + __uint_as_float(v3.y << 16);
      a3 += __uint_as_float(v0.y & 0xffff0000u) + __uint_as_float(v1.y & 0xffff0000u) +
            __uint_as_float(v2.y & 0xffff0000u) + __uint_as_float(v3.y & 0xffff0000u);
    }
    for (; j < m; j += 2) {              // tail pairs (possibly odd last edge)
      int e = j + half;
      int s = __shfl(cv, (e < m) ? e : 0);
      if (e < m) {
        uint2 v = *(const uint2*)&hbase[(size_t)s * NF];
        a0 += __uint_as_float(v.x << 16);
        a1 += __uint_as_float(v.x & 0xffff0000u);
        a2 += __uint_as_float(v.y << 16);
        a3 += __uint_as_float(v.y & 0xffff0000u);
      }
    }
  }
  // combine the two halves (feats identical, edge subsets disjoint)
  a0 += __shfl_xor(a0, 32);
  a1 += __shfl_xor(a1, 32);
  a2 += __shfl_xor(a2, 32);
  a3 += __shfl_xor(a3, 32);
  int d = end - beg;
  float inv = (d > 0) ? 1.0f / (float)d : 0.0f;
  if (half == 0) {
    uint2 o;
    o.x = (uint)f2bf(a0 * inv) | ((uint)f2bf(a1 * inv) << 16);
    o.y = (uint)f2bf(a2 * inv) | ((uint)f2bf(a3 * inv) << 16);
    *(uint2*)&aggr[(size_t)gw * NF + sl * 4] = o;
  }
}

// ---------------- MFMA GEMM: hout = relu([aggr|hin] @ [Wl;Wr] + b) ----------------
#define WSWZ(c, kbyte) (((c) << 9) + ((kbyte) ^ (((c) & 7) << 4)))

__global__ __launch_bounds__(256) void k_gemm_mfma(const ushort* __restrict__ aggr,
                                                   const ushort* __restrict__ hin,
                                                   ushort* __restrict__ hout,
                                                   const float* __restrict__ Wl,
                                                   const float* __restrict__ Wr,
                                                   const float* __restrict__ bias,
                                                   int n, int nslab) {
  __shared__ ushort Wt[128 * 256];   // [col][k] bf16, 64 KB, XOR-swizzled
  int t = threadIdx.x;
  for (int i = t; i < 128 * 128; i += 256) {
    int k = i >> 7, c = i & 127;
    *(ushort*)((char*)Wt + WSWZ(c, k * 2))         = f2bf(Wl[i]);
    *(ushort*)((char*)Wt + WSWZ(c, (k + 128) * 2)) = f2bf(Wr[i]);
  }
  __syncthreads();

  int wv = t >> 6, lane = t & 63;
  int c0 = wv * 32;
  int lrow = lane & 15, lhi = lane >> 4;

  bf16x8 bfrag[8][2];
  #pragma unroll
  for (int kc = 0; kc < 8; kc++)
    #pragma unroll
    for (int ct = 0; ct < 2; ct++) {
      int colv = c0 + ct * 16 + lrow;
      int kbyte = (kc * 32 + lhi * 8) * 2;
      bfrag[kc][ct] = *(const bf16x8*)((const char*)Wt + WSWZ(colv, kbyte));
    }
  float bv0 = bias[c0 + lrow], bv1 = bias[c0 + 16 + lrow];

  for (int sl = blockIdx.x; sl < nslab; sl += GEMM_BLOCKS) {
    int row0 = sl * 64;
    f32x4 acc[4][2];
    #pragma unroll
    for (int rt = 0; rt < 4; rt++)
      #pragma unroll
      for (int ct = 0; ct < 2; ct++) acc[rt][ct] = (f32x4){0.f, 0.f, 0.f, 0.f};

    #pragma unroll
    for (int kc = 0; kc < 8; kc++) {
      const ushort* Asrc = (kc < 4) ? aggr : hin;
      int k0 = (kc & 3) * 32 + lhi * 8;
      bf16x8 af[4];
      #pragma unroll
      for (int rt = 0; rt < 4; rt++) {
        int r = row0 + rt * 16 + lrow;
        if (r >= n) r = n - 1;
        af[rt] = *(const bf16x8*)&Asrc[(size_t)r * NF + k0];
      }
      #pragma unroll
      for (int rt = 0; rt < 4; rt++) {
        acc[rt][0] = __builtin_amdgcn_mfma_f32_16x16x32_bf16(af[rt], bfrag[kc][0], acc[rt][0], 0, 0, 0);
        acc[rt][1] = __builtin_amdgcn_mfma_f32_16x16x32_bf16(af[rt], bfrag[kc][1], acc[rt][1], 0, 0, 0);
      }
    }
    // C/D: col = lane&15, row = (lane>>4)*4 + reg   [m89-verified]
    #pragma unroll
    for (int rt = 0; rt < 4; rt++) {
      int rbase = row0 + rt * 16 + lhi * 4;
      #pragma unroll
      for (int r = 0; r < 4; r++) {
        int row = rbase + r;
        if (row < n) {
          hout[(size_t)row * NF + c0 + lrow]      = f2bf(fmaxf(acc[rt][0][r] + bv0, 0.f));
          hout[(size_t)row * NF + c0 + 16 + lrow] = f2bf(fmaxf(acc[rt][1][r] + bv1, 0.f));
        }
      }
    }
  }
}

// ---------------- pool + head ----------------
__global__ __launch_bounds__(128) void k_pool1(const ushort* __restrict__ h,
                                               float* __restrict__ partial, int n) {
  int f = threadIdx.x;
  float s = 0.f;
  for (int r = blockIdx.x; r < n; r += PB) s += b2f(h[(size_t)r * NF + f]);
  partial[blockIdx.x * NF + f] = s;
}

__global__ __launch_bounds__(128) void k_pool2(const float* __restrict__ partial,
                                               const float* __restrict__ Wg,
                                               const float* __restrict__ bg,
                                               float* __restrict__ out, int n) {
  __shared__ float g[NF];
  int f = threadIdx.x;
  float s = 0.f;
  for (int b = 0; b < PB; b++) s += partial[b * NF + f];
  g[f] = s / (float)n;
  __syncthreads();
  if (f < 64) {
    float z = bg[f];
    #pragma unroll 4
    for (int k = 0; k < NF; k++) z += g[k] * Wg[k * 64 + f];
    out[f] = 1.0f / (1.0f + expf(-z));
  }
}

// ---------------- launch ----------------
extern "C" void kernel_launch(void* const* d_in, const int* in_sizes, int n_in,
                              void* d_out, int out_size, void* d_ws, size_t ws_size,
                              hipStream_t stream) {
  const float* x   = (const float*)d_in[0];
  const int*   ei  = (const int*)d_in[1];
  const float* Wl1 = (const float*)d_in[2];
  const float* Wr1 = (const float*)d_in[3];
  const float* b1  = (const float*)d_in[4];
  const float* Wl2 = (const float*)d_in[5];
  const float* Wr2 = (const float*)d_in[6];
  const float* b2  = (const float*)d_in[7];
  const float* Wl3 = (const float*)d_in[8];
  const float* Wr3 = (const float*)d_in[9];
  const float* b3  = (const float*)d_in[10];
  const float* Wg  = (const float*)d_in[11];
  const float* bg  = (const float*)d_in[12];
  float* out = (float*)d_out;

  int n = in_sizes[0] / NF;      // 100000
  int E = in_sizes[1] / 2;       // 1600000
  const int* srcp = ei;
  const int* dstp = ei + E;

  char* w = (char*)d_ws;
  size_t off = 0;
  auto carve = [&](size_t bytes) -> void* {
    off = (off + 255) & ~(size_t)255;
    void* p = w + off;
    off += bytes;
    return p;
  };
  int nb = (n + SCAN_COVER - 1) / SCAN_COVER;
  int nbkt = (n + PART_NODES - 1) / PART_NODES;   // 196 coarse buckets
  int*    col       = (int*)   carve((size_t)E * 4);
  int*    row_start = (int*)   carve((size_t)(n + 1) * 4);
  int*    deg       = (int*)   carve((size_t)n * 4);
  int*    bsum      = (int*)   carve((size_t)nb * 4);
  int*    gcur      = (int*)   carve((size_t)256 * 4);
  ushort* xb        = (ushort*)carve((size_t)n * NF * 2);
  ushort* aggr      = (ushort*)carve((size_t)n * NF * 2);
  ushort* ha        = (ushort*)carve((size_t)n * NF * 2);
  ushort* hb        = (ushort*)carve((size_t)n * NF * 2);
  float*  partial   = (float*) carve((size_t)PB * NF * 4);
  uint*   bkt       = (uint*)hb;   // 4B-packed staging aliases hb (dead until layer 2)

  int eg = (E + 255) / 256;
  int ag = (n + 3) / 4;
  int nslab = (n + 63) / 64;
  int npart = (E + PART_CHUNK - 1) / PART_CHUNK;  // 391 partition blocks

  // convert x to bf16
  k_cvt<<<2048, 256, 0, stream>>>(x, xb, n * NF / 4);

  // CSR build: count -> scan -> block-reserved partition -> local fill
  hipMemsetAsync(deg, 0, (size_t)n * 4, stream);
  k_count<<<eg, 256, 0, stream>>>(dstp, deg, E);
  k_scan1<<<nb, 256, 0, stream>>>(deg, bsum, n);
  k_scan2<<<1, 128, 0, stream>>>(bsum, row_start, nb, n);
  k_scan3<<<nb, 256, 0, stream>>>(deg, bsum, row_start, n);
  k_gcur_init<<<1, 256, 0, stream>>>(row_start, gcur, nbkt);
  k_part<<<npart, 256, 0, stream>>>(srcp, dstp, gcur, bkt, E);
  k_fill3<<<nbkt, 256, 0, stream>>>(bkt, row_start, col, n);

  // layer 1: xb -> ha
  k_aggr_bf<<<ag, 256, 0, stream>>>(xb, row_start, col, aggr, n);
  k_gemm_mfma<<<GEMM_BLOCKS, 256, 0, stream>>>(aggr, xb, ha, Wl1, Wr1, b1, n, nslab);
  // layer 2: ha -> hb
  k_aggr_bf<<<ag, 256, 0, stream>>>(ha, row_start, col, aggr, n);
  k_gemm_mfma<<<GEMM_BLOCKS, 256, 0, stream>>>(aggr, ha, hb, Wl2, Wr2, b2, n, nslab);
  // layer 3: hb -> ha
  k_aggr_bf<<<ag, 256, 0, stream>>>(hb, row_start, col, aggr, n);
  k_gemm_mfma<<<GEMM_BLOCKS, 256, 0, stream>>>(aggr, hb, ha, Wl3, Wr3, b3, n, nslab);

  // pool + head
  k_pool1<<<PB, 128, 0, stream>>>(ha, partial, n);
  k_pool2<<<1, 128, 0, stream>>>(partial, Wg, bg, out, n);
}